// Round 2
// baseline (272.146 us; speedup 1.0000x reference)
//
#include <hip/hip_runtime.h>
#include <math.h>

#define EPSV 1e-6f
#define MAX_NORM (1.0f - 1e-3f)

typedef __attribute__((ext_vector_type(8))) short short8;   // 8 bf16 = 4 VGPRs
typedef __attribute__((ext_vector_type(4))) float f32x4;    // MFMA acc

// f32 -> bf16 (round-to-nearest-even), returns raw 16-bit pattern
__device__ inline ushort f32_to_bf16(float f) {
    union { float f; uint32_t u; } cv;
    cv.f = f;
    uint32_t u = cv.u;
    u += 0x7FFFu + ((u >> 16) & 1u);
    return (ushort)(u >> 16);
}

// ---------------------------------------------------------------------------
// Kernel 1: expmap0 + clip for embeddings. One wave (64 lanes) per row, D=512.
// Writes x_h (f32, into d_out region), bf16 copy (ws), x2_raw and (1 - c*x2).
// ---------------------------------------------------------------------------
__global__ void rows_emb_kernel(const float* __restrict__ emb,
                                const float* __restrict__ logc,
                                float* __restrict__ xh,
                                ushort* __restrict__ xbf,
                                float* __restrict__ x2raw,
                                float* __restrict__ dxv) {
    const int D = 512;
    const int row = blockIdx.x;
    const int lane = threadIdx.x;   // 0..63

    const float4* r4 = (const float4*)(emb + (size_t)row * D);
    float4 a = r4[2 * lane];
    float4 b = r4[2 * lane + 1];

    float ss = a.x * a.x + a.y * a.y + a.z * a.z + a.w * a.w
             + b.x * b.x + b.y * b.y + b.z * b.z + b.w * b.w;
#pragma unroll
    for (int off = 32; off > 0; off >>= 1) ss += __shfl_xor(ss, off, 64);

    const float c  = expf(logc[0]);
    const float sc = sqrtf(c);

    const float tn    = sqrtf(ss);                       // true norm
    const float vn    = fmaxf(tn, EPSV);                 // clamped norm
    const float coeff = tanhf(sc * vn) / (sc * vn);      // expmap0 coeff
    const float pre   = coeff * tn;                      // norm after expmap
    const float fac   = fminf(MAX_NORM / fmaxf(pre, EPSV), 1.0f);
    const float scale = coeff * fac;

    float4 oa, ob;
    oa.x = a.x * scale; oa.y = a.y * scale; oa.z = a.z * scale; oa.w = a.w * scale;
    ob.x = b.x * scale; ob.y = b.y * scale; ob.z = b.z * scale; ob.w = b.w * scale;

    float4* o4 = (float4*)(xh + (size_t)row * D);
    o4[2 * lane]     = oa;
    o4[2 * lane + 1] = ob;

    union { ushort u[8]; uint4 v; } pk;
    pk.u[0] = f32_to_bf16(oa.x); pk.u[1] = f32_to_bf16(oa.y);
    pk.u[2] = f32_to_bf16(oa.z); pk.u[3] = f32_to_bf16(oa.w);
    pk.u[4] = f32_to_bf16(ob.x); pk.u[5] = f32_to_bf16(ob.y);
    pk.u[6] = f32_to_bf16(ob.z); pk.u[7] = f32_to_bf16(ob.w);
    ((uint4*)(xbf + (size_t)row * D))[lane] = pk.v;

    if (lane == 0) {
        const float sq = scale * scale * ss;             // = sum(x_h^2)
        x2raw[row] = sq;
        dxv[row]   = 1.0f - c * fminf(sq, MAX_NORM * MAX_NORM);
    }
}

// ---------------------------------------------------------------------------
// Kernel 2: clip-only for centroids. One wave per row, D=512.
// ---------------------------------------------------------------------------
__global__ void rows_cen_kernel(const float* __restrict__ cen,
                                const float* __restrict__ logc,
                                float* __restrict__ ch,
                                ushort* __restrict__ cbf,
                                float* __restrict__ y2raw,
                                float* __restrict__ dyv) {
    const int D = 512;
    const int row = blockIdx.x;
    const int lane = threadIdx.x;

    const float4* r4 = (const float4*)(cen + (size_t)row * D);
    float4 a = r4[2 * lane];
    float4 b = r4[2 * lane + 1];

    float ss = a.x * a.x + a.y * a.y + a.z * a.z + a.w * a.w
             + b.x * b.x + b.y * b.y + b.z * b.z + b.w * b.w;
#pragma unroll
    for (int off = 32; off > 0; off >>= 1) ss += __shfl_xor(ss, off, 64);

    const float c = expf(logc[0]);

    const float tn    = sqrtf(ss);
    const float scale = fminf(MAX_NORM / fmaxf(tn, EPSV), 1.0f);

    float4 oa, ob;
    oa.x = a.x * scale; oa.y = a.y * scale; oa.z = a.z * scale; oa.w = a.w * scale;
    ob.x = b.x * scale; ob.y = b.y * scale; ob.z = b.z * scale; ob.w = b.w * scale;

    float4* o4 = (float4*)(ch + (size_t)row * D);
    o4[2 * lane]     = oa;
    o4[2 * lane + 1] = ob;

    union { ushort u[8]; uint4 v; } pk;
    pk.u[0] = f32_to_bf16(oa.x); pk.u[1] = f32_to_bf16(oa.y);
    pk.u[2] = f32_to_bf16(oa.z); pk.u[3] = f32_to_bf16(oa.w);
    pk.u[4] = f32_to_bf16(ob.x); pk.u[5] = f32_to_bf16(ob.y);
    pk.u[6] = f32_to_bf16(ob.z); pk.u[7] = f32_to_bf16(ob.w);
    ((uint4*)(cbf + (size_t)row * D))[lane] = pk.v;

    if (lane == 0) {
        const float sq = scale * scale * ss;
        y2raw[row] = sq;
        dyv[row]   = 1.0f - c * fminf(sq, MAX_NORM * MAX_NORM);
    }
}

// ---------------------------------------------------------------------------
// Kernel 3: bf16 MFMA GEMM xy = X @ Cen^T  (both row-major, K contiguous)
// fused with the Poincare-distance epilogue.
// 128x128 tile, BK=64, 4 waves (2x2), each wave computes 64x64 via 4x4
// fragments of mfma_f32_16x16x32_bf16. Single-buffered LDS, stride padded
// to 80 bf16 (160 B) to avoid the 128B-stride bank pathology.
// ---------------------------------------------------------------------------
#define BM 128
#define BN 128
#define BKT 64
#define LDST 80

__global__ __launch_bounds__(256)
void gemm_epi_kernel(const ushort* __restrict__ Abf,   // B x K bf16
                     const ushort* __restrict__ Bbf,   // C x K bf16
                     const float* __restrict__ x2raw,
                     const float* __restrict__ dxv,
                     const float* __restrict__ y2raw,
                     const float* __restrict__ dyv,
                     const float* __restrict__ logc,
                     float* __restrict__ out,          // B x C
                     int M, int N, int K) {
    __shared__ ushort As[BM * LDST];
    __shared__ ushort Bs[BN * LDST];

    const int tid  = threadIdx.x;
    const int lane = tid & 63;
    const int wid  = tid >> 6;
    const int wm   = wid >> 1;     // 0..1
    const int wn   = wid & 1;      // 0..1

    const int bm = blockIdx.y;
    const int bn = blockIdx.x;

    const ushort* Ab = Abf + (size_t)bm * BM * K;
    const ushort* Bb = Bbf + (size_t)bn * BN * K;

    f32x4 acc[4][4];
#pragma unroll
    for (int m = 0; m < 4; m++)
#pragma unroll
        for (int n = 0; n < 4; n++) acc[m][n] = (f32x4){0.f, 0.f, 0.f, 0.f};

    const int lr = lane & 15;          // fragment row (A) / col (B)
    const int lk = (lane >> 4) * 8;    // fragment k offset

    for (int k0 = 0; k0 < K; k0 += BKT) {
        // Stage A and B tiles: 128 rows x 64 k each; 16B chunks.
        // 1024 chunks / 256 threads = 4 per thread per tile.
#pragma unroll
        for (int i = 0; i < 4; i++) {
            const int chunk = tid + i * 256;
            const int row = chunk >> 3;
            const int cc  = chunk & 7;
            *(uint4*)(&As[row * LDST + cc * 8]) =
                *(const uint4*)(Ab + (size_t)row * K + k0 + cc * 8);
            *(uint4*)(&Bs[row * LDST + cc * 8]) =
                *(const uint4*)(Bb + (size_t)row * K + k0 + cc * 8);
        }
        __syncthreads();

#pragma unroll
        for (int kk = 0; kk < 2; kk++) {
            short8 af[4], bfr[4];
#pragma unroll
            for (int m = 0; m < 4; m++)
                af[m] = *(const short8*)(&As[(wm * 64 + m * 16 + lr) * LDST + kk * 32 + lk]);
#pragma unroll
            for (int n = 0; n < 4; n++)
                bfr[n] = *(const short8*)(&Bs[(wn * 64 + n * 16 + lr) * LDST + kk * 32 + lk]);
#pragma unroll
            for (int m = 0; m < 4; m++)
#pragma unroll
                for (int n = 0; n < 4; n++)
                    acc[m][n] = __builtin_amdgcn_mfma_f32_16x16x32_bf16(
                        af[m], bfr[n], acc[m][n], 0, 0, 0);
        }
        __syncthreads();
    }

    // Epilogue: dists = acosh(max(1 + 2c*diff2/denom, 1+eps)) / sqrt(c)
    const float c  = expf(logc[0]);
    const float sc = sqrtf(c);
    const int lg = lane >> 4;

#pragma unroll
    for (int m = 0; m < 4; m++) {
        const int gr0 = bm * BM + wm * 64 + m * 16 + lg * 4;
#pragma unroll
        for (int n = 0; n < 4; n++) {
            const int gc = bn * BN + wn * 64 + n * 16 + lr;
            const float ry = y2raw[gc];
            const float dy = dyv[gc];
#pragma unroll
            for (int r = 0; r < 4; r++) {
                const int gr = gr0 + r;
                const float rx = x2raw[gr];
                const float dx = dxv[gr];
                const float xy = acc[m][n][r];
                const float diff2 = rx + ry - 2.0f * xy;
                const float denom = fmaxf(dx * dy, EPSV);
                const float arg = fmaxf(1.0f + 2.0f * c * diff2 / denom, 1.0f + EPSV);
                out[(size_t)gr * N + gc] = acoshf(arg) / sc;
            }
        }
    }
}

// ---------------------------------------------------------------------------
extern "C" void kernel_launch(void* const* d_in, const int* in_sizes, int n_in,
                              void* d_out, int out_size, void* d_ws, size_t ws_size,
                              hipStream_t stream) {
    const float* emb  = (const float*)d_in[0];   // (B, D) f32
    const float* logc = (const float*)d_in[1];   // scalar f32
    const float* cen  = (const float*)d_in[2];   // (C, D) f32

    const int D = 512;
    const int B = in_sizes[0] / D;   // 8192
    const int C = in_sizes[2] / D;   // 4096

    float* out   = (float*)d_out;
    float* dists = out;                          // B*C
    float* xh    = out + (size_t)B * C;          // B*D
    float* ch    = xh + (size_t)B * D;           // C*D

    // Workspace layout (256B aligned blocks)
    char* ws = (char*)d_ws;
    size_t off = 0;
    auto alloc = [&](size_t bytes) -> char* {
        char* p = ws + off;
        off += (bytes + 255) & ~(size_t)255;
        return p;
    };
    ushort* xbf   = (ushort*)alloc((size_t)B * D * sizeof(ushort));
    ushort* cbf   = (ushort*)alloc((size_t)C * D * sizeof(ushort));
    float*  x2raw = (float*)alloc((size_t)B * sizeof(float));
    float*  dxv   = (float*)alloc((size_t)B * sizeof(float));
    float*  y2raw = (float*)alloc((size_t)C * sizeof(float));
    float*  dyv   = (float*)alloc((size_t)C * sizeof(float));

    rows_emb_kernel<<<B, 64, 0, stream>>>(emb, logc, xh, xbf, x2raw, dxv);
    rows_cen_kernel<<<C, 64, 0, stream>>>(cen, logc, ch, cbf, y2raw, dyv);

    dim3 grid(C / BN, B / BM);   // (32, 64)
    gemm_epi_kernel<<<grid, 256, 0, stream>>>(xbf, cbf, x2raw, dxv, y2raw, dyv,
                                              logc, dists, B, C, D);
}

// Round 3
// 161.625 us; speedup vs baseline: 1.6838x; 1.6838x over previous
//
#include <hip/hip_runtime.h>
#include <math.h>

#define EPSV 1e-6f
#define MAX_NORM (1.0f - 1e-3f)

typedef __attribute__((ext_vector_type(8))) short short8;   // 8 bf16 = 4 VGPRs
typedef __attribute__((ext_vector_type(4))) float f32x4;    // MFMA acc

// f32 -> bf16 (round-to-nearest-even), returns raw 16-bit pattern
__device__ inline ushort f32_to_bf16(float f) {
    union { float f; uint32_t u; } cv;
    cv.f = f;
    uint32_t u = cv.u;
    u += 0x7FFFu + ((u >> 16) & 1u);
    return (ushort)(u >> 16);
}

// async global -> LDS, 16 bytes per lane (dest = ldsbase + lane*16, contiguous)
__device__ inline void glds16(const ushort* gsrc, ushort* ldsdst) {
    auto* g = (const __attribute__((address_space(1))) uint32_t*)gsrc;
    auto* l = (__attribute__((address_space(3))) uint32_t*)ldsdst;
    __builtin_amdgcn_global_load_lds(g, l, 16, 0, 0);
}

// ---------------------------------------------------------------------------
// Kernel 1: expmap0 + clip for embeddings. One wave (64 lanes) per row, D=512.
// ---------------------------------------------------------------------------
__global__ void rows_emb_kernel(const float* __restrict__ emb,
                                const float* __restrict__ logc,
                                float* __restrict__ xh,
                                ushort* __restrict__ xbf,
                                float* __restrict__ x2raw,
                                float* __restrict__ dxv) {
    const int D = 512;
    const int row = blockIdx.x;
    const int lane = threadIdx.x;   // 0..63

    const float4* r4 = (const float4*)(emb + (size_t)row * D);
    float4 a = r4[2 * lane];
    float4 b = r4[2 * lane + 1];

    float ss = a.x * a.x + a.y * a.y + a.z * a.z + a.w * a.w
             + b.x * b.x + b.y * b.y + b.z * b.z + b.w * b.w;
#pragma unroll
    for (int off = 32; off > 0; off >>= 1) ss += __shfl_xor(ss, off, 64);

    const float c  = expf(logc[0]);
    const float sc = sqrtf(c);

    const float tn    = sqrtf(ss);
    const float vn    = fmaxf(tn, EPSV);
    const float coeff = tanhf(sc * vn) / (sc * vn);
    const float pre   = coeff * tn;
    const float fac   = fminf(MAX_NORM / fmaxf(pre, EPSV), 1.0f);
    const float scale = coeff * fac;

    float4 oa, ob;
    oa.x = a.x * scale; oa.y = a.y * scale; oa.z = a.z * scale; oa.w = a.w * scale;
    ob.x = b.x * scale; ob.y = b.y * scale; ob.z = b.z * scale; ob.w = b.w * scale;

    float4* o4 = (float4*)(xh + (size_t)row * D);
    o4[2 * lane]     = oa;
    o4[2 * lane + 1] = ob;

    union { ushort u[8]; uint4 v; } pk;
    pk.u[0] = f32_to_bf16(oa.x); pk.u[1] = f32_to_bf16(oa.y);
    pk.u[2] = f32_to_bf16(oa.z); pk.u[3] = f32_to_bf16(oa.w);
    pk.u[4] = f32_to_bf16(ob.x); pk.u[5] = f32_to_bf16(ob.y);
    pk.u[6] = f32_to_bf16(ob.z); pk.u[7] = f32_to_bf16(ob.w);
    ((uint4*)(xbf + (size_t)row * D))[lane] = pk.v;

    if (lane == 0) {
        const float sq = scale * scale * ss;
        x2raw[row] = sq;
        dxv[row]   = 1.0f - c * fminf(sq, MAX_NORM * MAX_NORM);
    }
}

// ---------------------------------------------------------------------------
// Kernel 2: clip-only for centroids. One wave per row, D=512.
// ---------------------------------------------------------------------------
__global__ void rows_cen_kernel(const float* __restrict__ cen,
                                const float* __restrict__ logc,
                                float* __restrict__ ch,
                                ushort* __restrict__ cbf,
                                float* __restrict__ y2raw,
                                float* __restrict__ dyv) {
    const int D = 512;
    const int row = blockIdx.x;
    const int lane = threadIdx.x;

    const float4* r4 = (const float4*)(cen + (size_t)row * D);
    float4 a = r4[2 * lane];
    float4 b = r4[2 * lane + 1];

    float ss = a.x * a.x + a.y * a.y + a.z * a.z + a.w * a.w
             + b.x * b.x + b.y * b.y + b.z * b.z + b.w * b.w;
#pragma unroll
    for (int off = 32; off > 0; off >>= 1) ss += __shfl_xor(ss, off, 64);

    const float c = expf(logc[0]);

    const float tn    = sqrtf(ss);
    const float scale = fminf(MAX_NORM / fmaxf(tn, EPSV), 1.0f);

    float4 oa, ob;
    oa.x = a.x * scale; oa.y = a.y * scale; oa.z = a.z * scale; oa.w = a.w * scale;
    ob.x = b.x * scale; ob.y = b.y * scale; ob.z = b.z * scale; ob.w = b.w * scale;

    float4* o4 = (float4*)(ch + (size_t)row * D);
    o4[2 * lane]     = oa;
    o4[2 * lane + 1] = ob;

    union { ushort u[8]; uint4 v; } pk;
    pk.u[0] = f32_to_bf16(oa.x); pk.u[1] = f32_to_bf16(oa.y);
    pk.u[2] = f32_to_bf16(oa.z); pk.u[3] = f32_to_bf16(oa.w);
    pk.u[4] = f32_to_bf16(ob.x); pk.u[5] = f32_to_bf16(ob.y);
    pk.u[6] = f32_to_bf16(ob.z); pk.u[7] = f32_to_bf16(ob.w);
    ((uint4*)(cbf + (size_t)row * D))[lane] = pk.v;

    if (lane == 0) {
        const float sq = scale * scale * ss;
        y2raw[row] = sq;
        dyv[row]   = 1.0f - c * fminf(sq, MAX_NORM * MAX_NORM);
    }
}

// ---------------------------------------------------------------------------
// Kernel 3: bf16 MFMA GEMM (m97 structure) + Poincare epilogue.
// 128x128 tile, BK=64, 4 waves (2x2), 4x4 frags of mfma_f32_16x16x32_bf16.
// Staging via global_load_lds width=16 into LINEAR LDS [128][64].
// ---------------------------------------------------------------------------
#define BM 128
#define BN 128
#define BKT 64

__global__ __launch_bounds__(256)
void gemm_epi_kernel(const ushort* __restrict__ Abf,   // M x K bf16
                     const ushort* __restrict__ Bbf,   // N x K bf16
                     const float* __restrict__ x2raw,
                     const float* __restrict__ dxv,
                     const float* __restrict__ y2raw,
                     const float* __restrict__ dyv,
                     const float* __restrict__ logc,
                     float* __restrict__ out,          // M x N
                     int M, int N, int K) {
    __shared__ ushort As[BM * BKT];   // 16 KB, linear (global_load_lds dest)
    __shared__ ushort Bs[BN * BKT];   // 16 KB

    const int tid  = threadIdx.x;
    const int lane = tid & 63;
    const int wid  = tid >> 6;
    const int wm   = wid >> 1;     // 0..1
    const int wn   = wid & 1;      // 0..1

    const int bm = blockIdx.y;
    const int bn = blockIdx.x;

    const ushort* Ab = Abf + (size_t)bm * BM * K;
    const ushort* Bb = Bbf + (size_t)bn * BN * K;

    f32x4 acc[4][4];
#pragma unroll
    for (int m = 0; m < 4; m++)
#pragma unroll
        for (int n = 0; n < 4; n++) acc[m][n] = (f32x4){0.f, 0.f, 0.f, 0.f};

    const int lr = lane & 15;          // fragment row (A) / col (B)
    const int lk = (lane >> 4) * 8;    // fragment k offset (bf16 elems)

    // staging geometry: each global_load_lds call moves 1024B = 8 rows x 128B.
    // lane l covers row (l>>3), bytes (l&7)*16 within the row.
    const int srow = lane >> 3;        // 0..7
    const int scol = (lane & 7) * 8;   // bf16 elems 0..56

    for (int k0 = 0; k0 < K; k0 += BKT) {
        // A-tile: 4 waves x 4 calls x 1KB = 16 KB; same for B.
#pragma unroll
        for (int j = 0; j < 4; j++) {
            const int row = wid * 32 + j * 8;
            glds16(Ab + (size_t)(row + srow) * K + k0 + scol, &As[row * BKT]);
            glds16(Bb + (size_t)(row + srow) * K + k0 + scol, &Bs[row * BKT]);
        }
        __syncthreads();   // compiler emits vmcnt(0) drain here (m97-known cost)

#pragma unroll
        for (int kk = 0; kk < 2; kk++) {
            short8 af[4], bfr[4];
#pragma unroll
            for (int m = 0; m < 4; m++)
                af[m] = *(const short8*)(&As[(wm * 64 + m * 16 + lr) * BKT + kk * 32 + lk]);
#pragma unroll
            for (int n = 0; n < 4; n++)
                bfr[n] = *(const short8*)(&Bs[(wn * 64 + n * 16 + lr) * BKT + kk * 32 + lk]);
#pragma unroll
            for (int m = 0; m < 4; m++)
#pragma unroll
                for (int n = 0; n < 4; n++)
                    acc[m][n] = __builtin_amdgcn_mfma_f32_16x16x32_bf16(
                        af[m], bfr[n], acc[m][n], 0, 0, 0);
        }
        __syncthreads();
    }

    // Epilogue: t = max(2c*diff2/denom, eps); dist = log(1+t+sqrt(t(t+2)))/sqrt(c)
    const float c   = expf(logc[0]);
    const float rsc = 1.0f / sqrtf(c);
    const int lg = lane >> 4;

#pragma unroll
    for (int n = 0; n < 4; n++) {
        const int gc = bn * BN + wn * 64 + n * 16 + lr;
        const float ry = y2raw[gc];
        const float dy = dyv[gc];
#pragma unroll
        for (int m = 0; m < 4; m++) {
            const int gr0 = bm * BM + wm * 64 + m * 16 + lg * 4;
#pragma unroll
            for (int r = 0; r < 4; r++) {
                const int gr = gr0 + r;
                const float rx = x2raw[gr];
                const float dx = dxv[gr];
                const float xy = acc[m][n][r];
                const float diff2 = rx + ry - 2.0f * xy;
                const float denom = fmaxf(dx * dy, EPSV);
                float t = 2.0f * c * diff2 / denom;
                t = fmaxf(t, EPSV);
                const float d = __logf(1.0f + t + sqrtf(t * (t + 2.0f))) * rsc;
                out[(size_t)gr * N + gc] = d;
            }
        }
    }
}

// ---------------------------------------------------------------------------
extern "C" void kernel_launch(void* const* d_in, const int* in_sizes, int n_in,
                              void* d_out, int out_size, void* d_ws, size_t ws_size,
                              hipStream_t stream) {
    const float* emb  = (const float*)d_in[0];   // (B, D) f32
    const float* logc = (const float*)d_in[1];   // scalar f32
    const float* cen  = (const float*)d_in[2];   // (C, D) f32

    const int D = 512;
    const int B = in_sizes[0] / D;   // 8192
    const int C = in_sizes[2] / D;   // 4096

    float* out   = (float*)d_out;
    float* dists = out;                          // B*C
    float* xh    = out + (size_t)B * C;          // B*D
    float* ch    = xh + (size_t)B * D;           // C*D

    char* ws = (char*)d_ws;
    size_t off = 0;
    auto alloc = [&](size_t bytes) -> char* {
        char* p = ws + off;
        off += (bytes + 255) & ~(size_t)255;
        return p;
    };
    ushort* xbf   = (ushort*)alloc((size_t)B * D * sizeof(ushort));
    ushort* cbf   = (ushort*)alloc((size_t)C * D * sizeof(ushort));
    float*  x2raw = (float*)alloc((size_t)B * sizeof(float));
    float*  dxv   = (float*)alloc((size_t)B * sizeof(float));
    float*  y2raw = (float*)alloc((size_t)C * sizeof(float));
    float*  dyv   = (float*)alloc((size_t)C * sizeof(float));

    rows_emb_kernel<<<B, 64, 0, stream>>>(emb, logc, xh, xbf, x2raw, dxv);
    rows_cen_kernel<<<C, 64, 0, stream>>>(cen, logc, ch, cbf, y2raw, dyv);

    dim3 grid(C / BN, B / BM);   // (32, 64)
    gemm_epi_kernel<<<grid, 256, 0, stream>>>(xbf, cbf, x2raw, dxv, y2raw, dyv,
                                              logc, dists, B, C, D);
}